// Round 2
// baseline (569.652 us; speedup 1.0000x reference)
//
#include <hip/hip_runtime.h>
#include <hip/hip_bf16.h>
#include <cstdint>
#include <cstddef>

// Problem constants (match reference)
#define B_TOT   2048
#define N_LIN   64
#define D_DIM   256
#define NSTEPS  4      // n_recurs + 1
#define BT      64     // batch rows per block

typedef __attribute__((ext_vector_type(8))) short short8;   // 8 bf16 = 4 VGPR
typedef __attribute__((ext_vector_type(4))) float f32x4;    // MFMA accumulator

// Split fp32 -> bf16 hi + bf16 lo (RNE both).  hi+lo reproduces f to ~2^-17 rel.
__device__ __forceinline__ void split2(float f, unsigned short& h, unsigned short& l) {
    unsigned u = __float_as_uint(f);
    unsigned r = u + 0x7FFFu + ((u >> 16) & 1u);
    h = (unsigned short)(r >> 16);
    float hf = __uint_as_float(r & 0xFFFF0000u);
    float rem = f - hf;
    unsigned u2 = __float_as_uint(rem);
    unsigned r2 = u2 + 0x7FFFu + ((u2 >> 16) & 1u);
    l = (unsigned short)(r2 >> 16);
}

__device__ __forceinline__ float bf16_to_f(unsigned short s) {
    return __uint_as_float((unsigned)s << 16);
}

// XOR-swizzled LDS index: logical (row r in [0,64), col c in [0,256)) ->
// physical ushort index.  Swizzle on 16-B (8-ushort) chunks: chunk ^= (r&7).
// Keeps total at exactly 64 KB (no padding) while spreading banks so the
// quad-strided ds_read_b128 A-fragment loads are only 2-way aliased (free).
__device__ __forceinline__ int swz(int r, int c) {
    return r * 256 + ((((c >> 3) ^ (r & 7))) << 3) + (c & 7);
}

// ---------------------------------------------------------------------------
// Prep (fast path only): masked weights -> bf16 hi/lo split arrays in d_ws.
// ---------------------------------------------------------------------------
__global__ void prep_kernel(const float* __restrict__ w, const float* __restrict__ wm,
                            unsigned short* __restrict__ w_hi,
                            unsigned short* __restrict__ w_lo) {
    const int nW4 = N_LIN * D_DIM * D_DIM / 4;   // 1,048,576 float4 groups
    int stride = gridDim.x * blockDim.x;
    for (int i = blockIdx.x * blockDim.x + threadIdx.x; i < nW4; i += stride) {
        float4 wv = ((const float4*)w)[i];
        float4 mv = ((const float4*)wm)[i];
        ushort4 h, l;
        split2(wv.x * mv.x, h.x, l.x);
        split2(wv.y * mv.y, h.y, l.y);
        split2(wv.z * mv.z, h.z, l.z);
        split2(wv.w * mv.w, h.w, l.w);
        ((ushort4*)w_hi)[i] = h;
        ((ushort4*)w_lo)[i] = l;
    }
}

// ---------------------------------------------------------------------------
// Fused 4-step recurrence.  One block = 64 batch rows x one linear n.
// x lives in LDS as bf16 hi/lo (swizzled, 64 KB total); 4 waves each own a
// 64-col output slice; 4x4 grid of 16x16x32 bf16 MFMA tiles per wave, with
// 3 products (hi*hi + hi*lo + lo*hi) for ~fp32 precision.
// ONFLY=true: no workspace — mask+split W from fp32 on the fly each k-tile.
// ---------------------------------------------------------------------------
template <bool ONFLY>
__global__ __launch_bounds__(256, 2)
void fused_kernel(const float* __restrict__ xin,
                  const unsigned short* __restrict__ w_hi,
                  const unsigned short* __restrict__ w_lo,
                  const float* __restrict__ wraw,
                  const float* __restrict__ wmask,
                  const float* __restrict__ braw,
                  const float* __restrict__ bmask,
                  float* __restrict__ xout) {
    __shared__ unsigned short xh[BT * 256];   // 32 KB
    __shared__ unsigned short xl[BT * 256];   // 32 KB  (total = 64 KB exactly)

    const int tid  = threadIdx.x;
    const int lane = tid & 63;
    const int wv   = tid >> 6;      // wave id -> col slice [wv*64, wv*64+64)
    const int quad = lane >> 4;
    const int l16  = lane & 15;

    // XCD-aware swizzle: all 32 batch-tiles of a given n share blockIdx%8,
    // so each XCD's L2 only holds 8 n's worth of weights (2 MB < 4 MB).
    const int xcd = blockIdx.x & 7;
    const int j8  = blockIdx.x >> 3;         // 0..255
    const int n   = (xcd << 3) | (j8 & 7);   // 0..63
    const int bt  = j8 >> 3;                 // 0..31

    const size_t row_stride = (size_t)N_LIN * D_DIM;  // 16384 floats between batch rows
    const float* xsrc = xin  + ((size_t)bt * BT * N_LIN + n) * D_DIM;
    float*       xdst = xout + ((size_t)bt * BT * N_LIN + n) * D_DIM;

    // ---- initial load: global fp32 -> LDS bf16 hi/lo (coalesced float4) ----
    for (int i = tid; i < BT * (D_DIM / 4); i += 256) {
        int r = i >> 6, c4 = i & 63;
        float4 v = ((const float4*)(xsrc + (size_t)r * row_stride))[c4];
        ushort4 h, l;
        split2(v.x, h.x, l.x);
        split2(v.y, h.y, l.y);
        split2(v.z, h.z, l.z);
        split2(v.w, h.w, l.w);
        int pi = r * 256 + ((((c4 >> 1) ^ (r & 7))) << 3) + ((c4 & 1) << 2);
        *((ushort4*)&xh[pi]) = h;
        *((ushort4*)&xl[pi]) = l;
    }

    // ---- per-lane masked bias for the 4 col-tiles ----
    float bias_r[4];
    float bmj[4];   // ONFLY: output-row mask scalar per col-tile
    #pragma unroll
    for (int ct = 0; ct < 4; ++ct) {
        int c = wv * 64 + ct * 16 + l16;
        float bm_c = bmask[n * D_DIM + c];
        bias_r[ct] = braw[n * D_DIM + c] * bm_c;
        bmj[ct] = bm_c;
    }

    // B-fragment base: lane covers w[j = wv*64 + ct*16 + l16][i = kt*32 + quad*8 .. +7]
    const size_t wbase = ((size_t)n * D_DIM + (size_t)wv * 64 + l16) * D_DIM + (size_t)quad * 8;

    __syncthreads();

    #pragma unroll 1
    for (int step = 0; step < NSTEPS; ++step) {
        f32x4 acc[4][4];
        #pragma unroll
        for (int rt = 0; rt < 4; ++rt)
            #pragma unroll
            for (int ct = 0; ct < 4; ++ct)
                acc[rt][ct] = f32x4{0.f, 0.f, 0.f, 0.f};

        #pragma unroll 2
        for (int kt = 0; kt < 8; ++kt) {
            // ---- B fragments ----
            short8 bh[4], bl[4];
            if (!ONFLY) {
                #pragma unroll
                for (int ct = 0; ct < 4; ++ct) {
                    size_t off = wbase + (size_t)ct * 16 * D_DIM + (size_t)kt * 32;
                    bh[ct] = *((const short8*)(w_hi + off));
                    bl[ct] = *((const short8*)(w_lo + off));
                }
            } else {
                // mask columns for this k-range
                const float* bmi_p = bmask + n * D_DIM + kt * 32 + quad * 8;
                float4 mi0 = ((const float4*)bmi_p)[0];
                float4 mi1 = ((const float4*)bmi_p)[1];
                float mi[8] = {mi0.x, mi0.y, mi0.z, mi0.w, mi1.x, mi1.y, mi1.z, mi1.w};
                #pragma unroll
                for (int ct = 0; ct < 4; ++ct) {
                    const float* wp = wraw + wbase + (size_t)ct * 16 * D_DIM + (size_t)kt * 32;
                    float4 w0 = ((const float4*)wp)[0];
                    float4 w1 = ((const float4*)wp)[1];
                    float wvv[8] = {w0.x, w0.y, w0.z, w0.w, w1.x, w1.y, w1.z, w1.w};
                    #pragma unroll
                    for (int j = 0; j < 8; ++j) {
                        unsigned short h, l;
                        split2(wvv[j] * bmj[ct] * mi[j], h, l);
                        bh[ct][j] = (short)h;
                        bl[ct][j] = (short)l;
                    }
                }
            }
            // ---- A fragments (LDS, swizzled; k0 is 8-aligned so one chunk) ----
            short8 ah[4], al[4];
            #pragma unroll
            for (int rt = 0; rt < 4; ++rt) {
                int m = rt * 16 + l16;
                int c0 = kt * 32 + quad * 8;
                int pi = m * 256 + ((((c0 >> 3) ^ (m & 7))) << 3);
                ah[rt] = *((const short8*)&xh[pi]);
                al[rt] = *((const short8*)&xl[pi]);
            }
            #pragma unroll
            for (int rt = 0; rt < 4; ++rt) {
                #pragma unroll
                for (int ct = 0; ct < 4; ++ct) {
                    acc[rt][ct] = __builtin_amdgcn_mfma_f32_16x16x32_bf16(ah[rt], bh[ct], acc[rt][ct], 0, 0, 0);
                    acc[rt][ct] = __builtin_amdgcn_mfma_f32_16x16x32_bf16(ah[rt], bl[ct], acc[rt][ct], 0, 0, 0);
                    acc[rt][ct] = __builtin_amdgcn_mfma_f32_16x16x32_bf16(al[rt], bh[ct], acc[rt][ct], 0, 0, 0);
                }
            }
        }

        __syncthreads();   // all waves' A-reads of x done before x is overwritten

        const bool last = (step == NSTEPS - 1);
        #pragma unroll
        for (int rt = 0; rt < 4; ++rt) {
            #pragma unroll
            for (int ct = 0; ct < 4; ++ct) {
                int c = wv * 64 + ct * 16 + l16;     // this lane's output column
                #pragma unroll
                for (int rg = 0; rg < 4; ++rg) {
                    int r = rt * 16 + quad * 4 + rg; // C/D layout: row = quad*4 + reg
                    int pi = swz(r, c);
                    float y   = acc[rt][ct][rg] + bias_r[ct];
                    float old = bf16_to_f(xh[pi]) + bf16_to_f(xl[pi]);
                    float xn  = old + fmaxf(y, 0.f);
                    if (last) {
                        xdst[(size_t)r * row_stride + c] = xn;
                    } else {
                        unsigned short h, l;
                        split2(xn, h, l);
                        xh[pi] = h;
                        xl[pi] = l;
                    }
                }
            }
        }
        __syncthreads();   // new x fully written before next step's A-reads
    }
}

// ---------------------------------------------------------------------------
extern "C" void kernel_launch(void* const* d_in, const int* in_sizes, int n_in,
                              void* d_out, int out_size, void* d_ws, size_t ws_size,
                              hipStream_t stream) {
    const float* x  = (const float*)d_in[0];
    const float* w  = (const float*)d_in[1];
    const float* b  = (const float*)d_in[2];
    const float* wm = (const float*)d_in[3];
    const float* bm = (const float*)d_in[4];
    float* out = (float*)d_out;

    const size_t needW = (size_t)2 * N_LIN * D_DIM * D_DIM * sizeof(unsigned short); // 16 MB
    const int grid = (B_TOT / BT) * N_LIN;   // 2048 blocks

    if (ws_size >= needW) {
        // Fast path: pre-split masked weights into workspace once per call.
        unsigned short* w_hi = (unsigned short*)d_ws;
        unsigned short* w_lo = w_hi + (size_t)N_LIN * D_DIM * D_DIM;
        prep_kernel<<<1024, 256, 0, stream>>>(w, wm, w_hi, w_lo);
        fused_kernel<false><<<grid, 256, 0, stream>>>(x, w_hi, w_lo, w, wm, b, bm, out);
    } else {
        // Fallback: no scratch — mask+split W on the fly inside the kernel.
        fused_kernel<true><<<grid, 256, 0, stream>>>(x, nullptr, nullptr, w, wm, b, bm, out);
    }
}